// Round 7
// baseline (213.937 us; speedup 1.0000x reference)
//
#include <hip/hip_runtime.h>

// CRF forward partition, MI355X. B=1024, L=512, T=52.
//
// R13 = R12 with DISJOINT broadcast mechanisms for the two waves.
// Evidence: R10 vs R12 — halving LDS reads changed nothing; cross-round fit
// wall/step = core(~630) + BOTH waves' issue => the two identical waves are
// phase-locked (DS bursts + stalls coincide; no mutual hiding; 631->838 when
// adding the 2nd wave). Fix: wave 0 (fwd) keeps the half-split LDS broadcast
// (R12); wave 1 (bwd) uses the R6-proven SGPR readlane broadcast (52x
// v_readlane fenced by sched_barrier; fmacs read SGPR x VGPR; ZERO LDS ops
// in its loop). Per-CU LDS waves drop 8 -> 4 (R7's level, where step=631),
// and wave 1's SGPR-hazard waits stall only itself, interleaving into wave
// 0's LDS-wait windows instead of colliding.
//
//   fwd:  u  = M_256...M_1 p0          (t = 1..256,   p'[j] = ef[j]*sum_i E[i][j] p[i])
//   bwd:  w <- E (ef_t (*) w)          (t = 511..257, w'[j] = sum_i E[j][i] ef[i] w[i])
//   out:  log(sum_j w[j]*u[j]) + shiftF + shiftB     (masked step = identity)

#define TT 52       // TAG_SIZE
#define LL 512      // sequence length
#define NS 8        // steps per group; normalize once per group

typedef float v2f __attribute__((ext_vector_type(2)));
typedef unsigned int uv2 __attribute__((ext_vector_type(2)));

__device__ __forceinline__ v2f pkfma(v2f a, v2f b, v2f c) {
#if __has_builtin(__builtin_elementwise_fma)
    return __builtin_elementwise_fma(a, b, c);   // lowers to v_pk_fma_f32
#else
    v2f r; r.x = fmaf(a.x, b.x, c.x); r.y = fmaf(a.y, b.y, c.y); return r;
#endif
}

__device__ __forceinline__ float rl(float x, int lane) {
    return __int_as_float(__builtin_amdgcn_readlane(__float_as_int(x), lane));
}

// Cross-half exchange: X[lane] = v[lane ^ 32]. One swap + one select.
__device__ __forceinline__ float xhalf(float v, bool hlo) {
#if __has_builtin(__builtin_amdgcn_permlane32_swap)
    uv2 r = __builtin_amdgcn_permlane32_swap(__float_as_uint(v),
                                             __float_as_uint(v), false, false);
    // r.x = [v.lo|v.lo], r.y = [v.hi|v.hi]   (verified: R11/R12 absmax 0.0)
    return hlo ? __uint_as_float(r.y) : __uint_as_float(r.x);
#else
    return __shfl_xor(v, 32, 64);
#endif
}

// Half-split matvec (wave 0 only). pqh = this half's 7 quads
// (p[28h .. 28h+27]). Ea/Eb pack coefficients for own column j / partner
// column j^32. Returns full sum_i E[i]*p[i] for column j.
__device__ __forceinline__ float matvec52h(const float4* pqh, const v2f* Ea,
                                           const v2f* Eb, bool hlo) {
    v2f a0 = {0.f, 0.f}, a1 = {0.f, 0.f};   // own column (2 chains of 7)
    v2f b0 = {0.f, 0.f}, b1 = {0.f, 0.f};   // partner column
#pragma unroll
    for (int q = 0; q < 7; ++q) {
        float4 Q = pqh[q];
        v2f lo = {Q.x, Q.y};
        v2f hi = {Q.z, Q.w};
        a0 = pkfma(lo, Ea[2 * q + 0], a0);
        a1 = pkfma(hi, Ea[2 * q + 1], a1);
        b0 = pkfma(lo, Eb[2 * q + 0], b0);
        b1 = pkfma(hi, Eb[2 * q + 1], b1);
    }
    v2f s1 = a0 + a1;
    v2f s2 = b0 + b1;
    float P1 = s1.x + s1.y;
    float P2 = s2.x + s2.y;
    return P1 + xhalf(P2, hlo);
}

__global__ void __launch_bounds__(128)
__attribute__((amdgpu_waves_per_eu(2, 2)))
crf_fwd(
    const float* __restrict__ feats,   // (B, L, T)
    const int*   __restrict__ mask,    // (B, L)
    const float* __restrict__ trans,   // (T, T)
    float*       __restrict__ out)     // scalar accumulator (pre-zeroed)
{
    __shared__ __align__(16) float plds[2][64];  // [0]: fwd broadcast, [1]: combine only
    __shared__ float shsh[2];                    // per-wave shift handoff

    const int b   = blockIdx.x;
    const int tid = threadIdx.x;
    const int w   = tid >> 6;           // 0 = fwd wave (LDS), 1 = bwd wave (SGPR)
    const int j   = tid & 63;           // lane = tag (column owner)
    const bool act = (j < TT);
    const int jc = act ? j : 0;         // clamped index for safe loads

    const float* fb = feats + (size_t)b * LL * TT;
    const int*   mb = mask  + (size_t)b * LL;

    float pv;      // this wave's state entry (p[j] fwd / w[j] bwd)
    float shift;   // log of accumulated normalization factors

    if (w == 0) {
        // ------------- forward chain (LDS half-split broadcast): t = 1..256 -
        const int h   = j >> 5;             // lane half
        const bool hlo = (h == 0);
        const int jx  = j ^ 32;             // partner column
        const int i0  = 28 * h;             // this half's i-range start

        v2f Ea[14], Eb[14];
#pragma unroll
        for (int k = 0; k < 14; ++k) {
            int ia = i0 + 2 * k, ib = ia + 1;
            int iac = ia < TT ? ia : 0, ibc = ib < TT ? ib : 0;
            int jxc = jx < TT ? jx : 0;
            float eax = __expf(trans[iac * TT + jc]);
            float eay = __expf(trans[ibc * TT + jc]);
            float ebx = __expf(trans[iac * TT + jxc]);
            float eby = __expf(trans[ibc * TT + jxc]);
            Ea[k].x = (ia < TT && j  < TT) ? eax : 0.0f;
            Ea[k].y = (ib < TT && j  < TT) ? eay : 0.0f;
            Eb[k].x = (ia < TT && jx < TT) ? ebx : 0.0f;
            Eb[k].y = (ib < TT && jx < TT) ? eby : 0.0f;
        }

        // t=0 init: part0[j] = feats[b,0,j] + trans[START][j]; normalize.
        float part0 = act ? (fb[j] + trans[(TT - 2) * TT + j]) : -1.0e30f;
        shift = rl(part0, 0);
        pv = act ? __expf(part0 - shift) : 0.0f;
        plds[0][j] = pv;                 // lanes >= TT write pad zeros

        const float4* pqh = ((const float4*)plds[0]) + 7 * h;

        float fA[NS], fB[NS]; int mA[NS], mB[NS];
#pragma unroll
        for (int u = 0; u < NS; ++u) {
            fA[u] = fb[(1 + u) * TT + jc];
            mA[u] = mb[1 + u];
        }

        auto fwd_group = [&](float (&fp)[NS], int (&mc)[NS],
                             float (&fn)[NS], int (&mn)[NS], int t0) {
#pragma unroll
            for (int u = 0; u < NS; ++u) {
                int tn = t0 + NS + u;            // <= 264 < LL, in-bounds
                fn[u] = fb[tn * TT + jc];
                mn[u] = mb[tn];
            }
            float ef[NS];
#pragma unroll
            for (int u = 0; u < NS; ++u) ef[u] = __expf(fp[u]);
#pragma unroll
            for (int u = 0; u < NS; ++u) {
                float pn = matvec52h(pqh, Ea, Eb, hlo) * ef[u];
                pv = (mc[u] > 0) ? pn : pv;      // branchless mask select
                if (u == NS - 1) {
                    float c = rl(pv, 0);
                    shift += __logf(c);
                    pv *= __builtin_amdgcn_rcpf(c);
                }
                plds[0][j] = pv;                 // broadcast for next step
            }
        };

        // 32 groups (t0 = 1..249) as 16 ping-pong pairs: t = 1..256 exactly.
        for (int t0 = 1; t0 <= 241; t0 += 2 * NS) {
            fwd_group(fA, mA, fB, mB, t0);
            fwd_group(fB, mB, fA, mA, t0 + NS);
        }
    } else {
        // ------------- backward chain (SGPR readlane broadcast): t = 511..257
        // E row j in VGPRs: E[i] = exp(trans[j][i]); -1000 entries -> exact 0.
        float E[TT];
#pragma unroll
        for (int i = 0; i < TT; ++i) {
            float e = __expf(trans[jc * TT + i]);
            E[i] = act ? e : 0.0f;
        }

        // init: w[j] = exp(trans[j][END])
        pv = act ? __expf(trans[jc * TT + (TT - 1)]) : 0.0f;
        shift = 0.0f;

        // Wave-uniform broadcast buffer (targets SGPRs via readlane).
        float ps[TT];

        float fA[NS], fB[NS]; int mA[NS], mB[NS];
#pragma unroll
        for (int u = 0; u < NS; ++u) {
            fA[u] = fb[(LL - 1 - u) * TT + jc];
            mA[u] = mb[LL - 1 - u];
        }

        auto bwd_group = [&](float (&fp)[NS], int (&mc)[NS],
                             float (&fn)[NS], int (&mn)[NS], int g) {
#pragma unroll
            for (int u = 0; u < NS; ++u) {
                int kn = g + NS + u;             // <= 255 -> t >= 256, in-bounds
                fn[u] = fb[(LL - 1 - kn) * TT + jc];
                mn[u] = mb[LL - 1 - kn];
            }
            float ef[NS];
#pragma unroll
            for (int u = 0; u < NS; ++u) ef[u] = __expf(fp[u]);
#pragma unroll
            for (int u = 0; u < NS; ++u) {
                // broadcast q = ef (*) w: hazard-free readlane block (R6).
                float bv = ef[u] * pv;
                __builtin_amdgcn_sched_barrier(0);
#pragma unroll
                for (int i = 0; i < TT; ++i) ps[i] = rl(bv, i);
                __builtin_amdgcn_sched_barrier(0);
                // w'[j] = sum_i E[j][i] q[i]  (4 independent FMA chains)
                float a0 = 0.f, a1 = 0.f, a2 = 0.f, a3 = 0.f;
#pragma unroll
                for (int i = 0; i < TT; i += 4) {
                    a0 = fmaf(ps[i + 0], E[i + 0], a0);
                    a1 = fmaf(ps[i + 1], E[i + 1], a1);
                    a2 = fmaf(ps[i + 2], E[i + 2], a2);
                    a3 = fmaf(ps[i + 3], E[i + 3], a3);
                }
                float wn = ((a0 + a1) + (a2 + a3));
                pv = (mc[u] > 0) ? wn : pv;      // branchless mask select
                if (u == NS - 1) {
                    float c = rl(pv, 0);
                    shift += __logf(c);
                    pv *= __builtin_amdgcn_rcpf(c);
                }
            }
        };

        // 30 groups as 15 ping-pong pairs (k = 0..239), 1 single group
        // (k = 240..247, prefetches k = 248..255 into fB), then 7-step tail.
        for (int g = 0; g <= 224; g += 2 * NS) {
            bwd_group(fA, mA, fB, mB, g);
            bwd_group(fB, mB, fA, mA, g + NS);
        }
        bwd_group(fA, mA, fB, mB, 240);

        // Tail: 7 steps, k = 248..254 (data in fB[0..6]).
#pragma unroll
        for (int u = 0; u < 7; ++u) {
            float bv = __expf(fB[u]) * pv;
            __builtin_amdgcn_sched_barrier(0);
#pragma unroll
            for (int i = 0; i < TT; ++i) ps[i] = rl(bv, i);
            __builtin_amdgcn_sched_barrier(0);
            float a0 = 0.f, a1 = 0.f, a2 = 0.f, a3 = 0.f;
#pragma unroll
            for (int i = 0; i < TT; i += 4) {
                a0 = fmaf(ps[i + 0], E[i + 0], a0);
                a1 = fmaf(ps[i + 1], E[i + 1], a1);
                a2 = fmaf(ps[i + 2], E[i + 2], a2);
                a3 = fmaf(ps[i + 3], E[i + 3], a3);
            }
            float wn = ((a0 + a1) + (a2 + a3));
            pv = (mB[u] > 0) ? wn : pv;
        }

        // Final safety normalize (bounds w away from inf before combine).
        {
            float c = rl(pv, 0);
            shift += __logf(c);
            pv *= __builtin_amdgcn_rcpf(c);
        }
    }

    // ---------------- combine: S = log(sum_j w[j]*u[j]) + shiftF + shiftB ----
    plds[w][j] = pv;
    if (j == 0) shsh[w] = shift;
    __syncthreads();

    if (w == 0) {
        float wj  = plds[1][j];                  // bwd vector (0 for j >= TT)
        float val = act ? (pv * wj) : 0.0f;
#pragma unroll
        for (int o = 32; o >= 1; o >>= 1)
            val += __shfl_xor(val, o, 64);
        if (j == 0) atomicAdd(out, __logf(val) + shift + shsh[1]);
    }
}

extern "C" void kernel_launch(void* const* d_in, const int* in_sizes, int n_in,
                              void* d_out, int out_size, void* d_ws, size_t ws_size,
                              hipStream_t stream) {
    const float* feats = (const float*)d_in[0];
    const int*   mask  = (const int*)d_in[1];
    const float* trans = (const float*)d_in[2];
    float* out = (float*)d_out;

    const int B = in_sizes[1] / LL;   // mask is (B, L)

    hipMemsetAsync(d_out, 0, sizeof(float), stream);
    crf_fwd<<<B, 128, 0, stream>>>(feats, mask, trans, out);
}